// Round 6
// baseline (299.765 us; speedup 1.0000x reference)
//
#include <hip/hip_runtime.h>

#define NNODES 50000
#define DIM 128
#define LDT 136   // agg LDS row stride in bf16 units (128 + 8 pad, 16B-aligned)

typedef __attribute__((ext_vector_type(8))) __bf16 bf16x8;
typedef __attribute__((ext_vector_type(4))) float f32x4;

__device__ inline unsigned short f2b(float f) {           // RNE fp32->bf16
    unsigned int u = __float_as_uint(f);
    u += 0x7fffu + ((u >> 16) & 1u);
    return (unsigned short)(u >> 16);
}
__device__ inline float blo(unsigned int u) { return __uint_as_float(u << 16); }
__device__ inline float bhi(unsigned int u) { return __uint_as_float(u & 0xffff0000u); }
__device__ inline unsigned int pack2(float a, float b) {
    return (unsigned int)f2b(a) | ((unsigned int)f2b(b) << 16);
}

// ===========================================================================
// Casts (once per call)
// ===========================================================================
__global__ __launch_bounds__(256) void k_cast_f4(
    const float* __restrict__ src, unsigned short* __restrict__ dst, int n4)
{
    int i = blockIdx.x * 256 + threadIdx.x;
    if (i >= n4) return;
    float4 v = reinterpret_cast<const float4*>(src)[i];
    uint2 o;
    o.x = pack2(v.x, v.y);
    o.y = pack2(v.z, v.w);
    reinterpret_cast<uint2*>(dst)[i] = o;
}

__global__ __launch_bounds__(256) void k_cast_weights(
    const float* __restrict__ Wa1, const float* __restrict__ Wb1,
    const float* __restrict__ Wa2, const float* __restrict__ Wb2,
    unsigned short* __restrict__ wa1, unsigned short* __restrict__ wb1,
    unsigned short* __restrict__ wa2, unsigned short* __restrict__ wb2)
{
    int i = blockIdx.x * 256 + threadIdx.x;
    if (i < 16384) { wa1[i] = f2b(Wa1[i]); wb1[i] = f2b(Wb1[i]); }
    if (i < 8192)  { wa2[i] = f2b(Wa2[i]); wb2[i] = f2b(Wb2[i]); }
}

// ===========================================================================
// CSR build (per call; graph static within a call, reused by both layers)
// ===========================================================================
__global__ __launch_bounds__(256) void k_hist(
    const int* __restrict__ dst, int* __restrict__ counts, int n_edges)
{
    int e = blockIdx.x * blockDim.x + threadIdx.x;
    if (e >= n_edges) return;
    atomicAdd(&counts[dst[e]], 1);
}

// 2-level scan: 13 blocks x 1024 thr x int4. Local exclusive scan + block sum.
__global__ __launch_bounds__(1024) void k_scan_local(
    const int* __restrict__ counts, int* __restrict__ rowptr,
    int* __restrict__ bsum, int n)
{
    __shared__ int wsum[16];
    const int lane = threadIdx.x & 63;
    const int wid = threadIdx.x >> 6;
    int i = blockIdx.x * 4096 + threadIdx.x * 4;
    int4 v = make_int4(0, 0, 0, 0);
    if (i + 3 < n) {
        v = *reinterpret_cast<const int4*>(counts + i);
    } else {
        if (i + 0 < n) v.x = counts[i + 0];
        if (i + 1 < n) v.y = counts[i + 1];
        if (i + 2 < n) v.z = counts[i + 2];
    }
    int tot = v.x + v.y + v.z + v.w;
    int s = tot;
#pragma unroll
    for (int off = 1; off < 64; off <<= 1) {
        int t = __shfl_up(s, off);
        if (lane >= off) s += t;
    }
    if (lane == 63) wsum[wid] = s;
    __syncthreads();
    if (wid == 0 && lane < 16) {
        int ws = wsum[lane];
#pragma unroll
        for (int off = 1; off < 16; off <<= 1) {
            int t = __shfl_up(ws, off);
            if (lane >= off) ws += t;
        }
        wsum[lane] = ws;
    }
    __syncthreads();
    int prefix = ((wid > 0) ? wsum[wid - 1] : 0) + (s - tot);
    int4 o;
    o.x = prefix;
    o.y = prefix + v.x;
    o.z = o.y + v.y;
    o.w = o.z + v.z;
    if (i + 3 < n) {
        *reinterpret_cast<int4*>(rowptr + i) = o;
    } else {
        if (i + 0 < n) rowptr[i + 0] = o.x;
        if (i + 1 < n) rowptr[i + 1] = o.y;
        if (i + 2 < n) rowptr[i + 2] = o.z;
    }
    if (threadIdx.x == 1023) bsum[blockIdx.x] = wsum[15];
}

// Add scanned block offsets; block 0 thread 0 writes rowptr[n] = total.
__global__ __launch_bounds__(1024) void k_scan_add(
    int* __restrict__ rowptr, const int* __restrict__ bsum, int n, int nblk)
{
    int off = 0, total = 0;
    for (int j = 0; j < nblk; ++j) {
        int b = bsum[j];
        if (j < (int)blockIdx.x) off += b;
        total += b;
    }
    if (blockIdx.x == 0 && threadIdx.x == 0) rowptr[n] = total;
    if (blockIdx.x == 0) return;                 // offset 0
    int i = blockIdx.x * 4096 + threadIdx.x * 4;
    if (i + 3 < n) {
        int4 v = *reinterpret_cast<const int4*>(rowptr + i);
        v.x += off; v.y += off; v.z += off; v.w += off;
        *reinterpret_cast<int4*>(rowptr + i) = v;
    } else {
        if (i + 0 < n) rowptr[i + 0] += off;
        if (i + 1 < n) rowptr[i + 1] += off;
        if (i + 2 < n) rowptr[i + 2] += off;
    }
}

__global__ __launch_bounds__(256) void k_place(
    const int* __restrict__ src, const int* __restrict__ dst,
    const int* __restrict__ rowptr, int* __restrict__ cursor,
    int* __restrict__ srcs_sorted, int n_edges)
{
    int e = blockIdx.x * blockDim.x + threadIdx.x;
    if (e >= n_edges) return;
    int d = dst[e];
    int pos = rowptr[d] + atomicAdd(&cursor[d], 1);
    srcs_sorted[pos] = src[e];
}

// ===========================================================================
// Fused layer: per 64-node block
//   phase A: gather-sum neighbor rows (bf16 in, fp32 acc) -> LDS agg tile
//   phase B: C[n,:] = act( agg @ Wa^T + root @ Wb^T + bias ) via 16x16x32 MFMA
// Root A-fragments and weight B-fragments are read DIRECT from global
// (weights L2-resident; no staging barriers -> only one barrier per block).
// ks loops are unroll-1: full unroll hoists 64 b128 loads -> VGPR blowup (R1/R4).
// ===========================================================================
template <int BN, bool RELU, bool OUTBF16>
__global__ __launch_bounds__(256) void k_fused_layer(
    const unsigned short* __restrict__ xb,   // features [n,128] bf16 (gather src AND root)
    const int* __restrict__ rowptr, const int* __restrict__ srcs,
    const unsigned short* __restrict__ Wa,   // [BN,128] bf16
    const unsigned short* __restrict__ Wb,   // [BN,128] bf16
    const float* __restrict__ bias, void* __restrict__ Cout, int n_nodes)
{
    constexpr int NT = BN / 16;              // 8 (layer1) or 4 (layer2)
    __shared__ unsigned short aggs[64 * LDT];

    const int tid = threadIdx.x;
    const int n0 = blockIdx.x * 64;

    // ---- phase A: gather 64 nodes, 16 lane-groups x 4 nodes each ----
    {
        const int g = tid >> 4;
        const int seg = tid & 15;            // 16B col segment
#pragma unroll 1
        for (int i = 0; i < 4; ++i) {
            int local = g * 4 + i;
            int node = n0 + local;
            float acc[8];
#pragma unroll
            for (int k = 0; k < 8; ++k) acc[k] = 0.f;
            if (node < n_nodes) {
                int e = rowptr[node], end = rowptr[node + 1];
                for (; e + 1 < end; e += 2) {
                    int s0 = srcs[e], s1 = srcs[e + 1];
                    uint4 v0 = *reinterpret_cast<const uint4*>(xb + (size_t)s0 * DIM + seg * 8);
                    uint4 v1 = *reinterpret_cast<const uint4*>(xb + (size_t)s1 * DIM + seg * 8);
                    acc[0] += blo(v0.x) + blo(v1.x); acc[1] += bhi(v0.x) + bhi(v1.x);
                    acc[2] += blo(v0.y) + blo(v1.y); acc[3] += bhi(v0.y) + bhi(v1.y);
                    acc[4] += blo(v0.z) + blo(v1.z); acc[5] += bhi(v0.z) + bhi(v1.z);
                    acc[6] += blo(v0.w) + blo(v1.w); acc[7] += bhi(v0.w) + bhi(v1.w);
                }
                if (e < end) {
                    int s0 = srcs[e];
                    uint4 v0 = *reinterpret_cast<const uint4*>(xb + (size_t)s0 * DIM + seg * 8);
                    acc[0] += blo(v0.x); acc[1] += bhi(v0.x);
                    acc[2] += blo(v0.y); acc[3] += bhi(v0.y);
                    acc[4] += blo(v0.z); acc[5] += bhi(v0.z);
                    acc[6] += blo(v0.w); acc[7] += bhi(v0.w);
                }
            }
            uint4 o;
            o.x = pack2(acc[0], acc[1]);
            o.y = pack2(acc[2], acc[3]);
            o.z = pack2(acc[4], acc[5]);
            o.w = pack2(acc[6], acc[7]);
            *reinterpret_cast<uint4*>(&aggs[local * LDT + seg * 8]) = o;
        }
    }
    __syncthreads();

    // ---- phase B: dual MFMA GEMM ----
    const int wave = tid >> 6;
    const int lane = tid & 63;
    const int quad = lane >> 4;
    const int l16 = lane & 15;
    const int arow = n0 + wave * 16 + l16;
    const bool arow_ok = arow < n_nodes;

    f32x4 acc[NT];
#pragma unroll
    for (int nt = 0; nt < NT; ++nt) {
        f32x4 z = {0.f, 0.f, 0.f, 0.f};
        acc[nt] = z;
    }

    // agg @ Wa^T : A from LDS agg tile
#pragma unroll 1
    for (int ks = 0; ks < 4; ++ks) {
        bf16x8 a = *reinterpret_cast<const bf16x8*>(
            &aggs[(wave * 16 + l16) * LDT + ks * 32 + quad * 8]);
#pragma unroll
        for (int nt = 0; nt < NT; ++nt) {
            bf16x8 b = *reinterpret_cast<const bf16x8*>(
                Wa + (size_t)(nt * 16 + l16) * DIM + ks * 32 + quad * 8);
            acc[nt] = __builtin_amdgcn_mfma_f32_16x16x32_bf16(a, b, acc[nt], 0, 0, 0);
        }
    }
    // root @ Wb^T : A direct from global feature rows
#pragma unroll 1
    for (int ks = 0; ks < 4; ++ks) {
        bf16x8 a = {};
        if (arow_ok)
            a = *reinterpret_cast<const bf16x8*>(
                xb + (size_t)arow * DIM + ks * 32 + quad * 8);
#pragma unroll
        for (int nt = 0; nt < NT; ++nt) {
            bf16x8 b = *reinterpret_cast<const bf16x8*>(
                Wb + (size_t)(nt * 16 + l16) * DIM + ks * 32 + quad * 8);
            acc[nt] = __builtin_amdgcn_mfma_f32_16x16x32_bf16(a, b, acc[nt], 0, 0, 0);
        }
    }

    // epilogue: C row = n0 + wave*16 + quad*4 + reg, col = nt*16 + l16
#pragma unroll
    for (int nt = 0; nt < NT; ++nt) {
        int col = nt * 16 + l16;
        float bv = bias[col];
#pragma unroll
        for (int reg = 0; reg < 4; ++reg) {
            int row = n0 + wave * 16 + quad * 4 + reg;
            if (row >= n_nodes) continue;
            float v = acc[nt][reg] + bv;
            if (RELU) v = fmaxf(v, 0.f);
            if (OUTBF16)
                ((unsigned short*)Cout)[(size_t)row * BN + col] = f2b(v);
            else
                ((float*)Cout)[(size_t)row * BN + col] = v;
        }
    }
}

extern "C" void kernel_launch(void* const* d_in, const int* in_sizes, int n_in,
                              void* d_out, int out_size, void* d_ws, size_t ws_size,
                              hipStream_t stream) {
    const float* x       = (const float*)d_in[0];
    const int*   ei      = (const int*)d_in[1];
    const float* W_rel1  = (const float*)d_in[2];
    const float* W_root1 = (const float*)d_in[3];
    const float* b1      = (const float*)d_in[4];
    const float* W_rel2  = (const float*)d_in[5];
    const float* W_root2 = (const float*)d_in[6];
    const float* b2      = (const float*)d_in[7];

    const int n_edges = in_sizes[1] / 2;
    const int* src = ei;
    const int* dst = ei + n_edges;

    // workspace layout (all 16B-aligned)
    const size_t NELEM = (size_t)NNODES * DIM;            // 6.4M
    unsigned short* xb  = (unsigned short*)d_ws;          // 12.8 MB
    unsigned short* tb  = xb + NELEM;                     // 12.8 MB
    unsigned short* wa1 = tb + NELEM;                     // 16384
    unsigned short* wb1 = wa1 + 16384;
    unsigned short* wa2 = wb1 + 16384;                    // 8192
    unsigned short* wb2 = wa2 + 8192;
    int* rowptr = (int*)(wb2 + 8192);                     // NNODES+4
    int* cursor = rowptr + (NNODES + 4);                  // NNODES
    int* bsum   = cursor + NNODES;                        // 16
    int* srcs   = bsum + 16;                              // n_edges

    float* out = (float*)d_out;

    const int eblocks = (n_edges + 255) / 256;
    const int fblocks = (NNODES + 63) / 64;
    const int sblocks = (NNODES + 4095) / 4096;           // 13
    const int n4 = NNODES * DIM / 4;

    // ---- casts ----
    k_cast_f4<<<(n4 + 255) / 256, 256, 0, stream>>>(x, xb, n4);
    k_cast_weights<<<64, 256, 0, stream>>>(W_rel1, W_root1, W_rel2, W_root2,
                                           wa1, wb1, wa2, wb2);

    // ---- CSR build ----
    hipMemsetAsync(cursor, 0, NNODES * sizeof(int), stream);
    k_hist<<<eblocks, 256, 0, stream>>>(dst, cursor, n_edges);
    k_scan_local<<<sblocks, 1024, 0, stream>>>(cursor, rowptr, bsum, NNODES);
    k_scan_add<<<sblocks, 1024, 0, stream>>>(rowptr, bsum, NNODES, sblocks);
    hipMemsetAsync(cursor, 0, NNODES * sizeof(int), stream);
    k_place<<<eblocks, 256, 0, stream>>>(src, dst, rowptr, cursor, srcs, n_edges);

    // ---- layer 1 (x -> tb, relu, bf16 out) ----
    k_fused_layer<128, true, true><<<fblocks, 256, 0, stream>>>(
        xb, rowptr, srcs, wa1, wb1, b1, tb, NNODES);

    // ---- layer 2 (tb -> out, fp32 out) ----
    k_fused_layer<64, false, false><<<fblocks, 256, 0, stream>>>(
        tb, rowptr, srcs, wa2, wb2, b2, out, NNODES);
}

// Round 7
// 285.858 us; speedup vs baseline: 1.0486x; 1.0486x over previous
//
#include <hip/hip_runtime.h>

#define NNODES 50000
#define DIM 128

typedef __attribute__((ext_vector_type(8))) __bf16 bf16x8;
typedef __attribute__((ext_vector_type(4))) float f32x4;

__device__ inline unsigned short f2b(float f) {           // RNE fp32->bf16
    unsigned int u = __float_as_uint(f);
    u += 0x7fffu + ((u >> 16) & 1u);
    return (unsigned short)(u >> 16);
}
__device__ inline float blo(unsigned int u) { return __uint_as_float(u << 16); }
__device__ inline float bhi(unsigned int u) { return __uint_as_float(u & 0xffff0000u); }
__device__ inline unsigned int pack2(float a, float b) {
    return (unsigned int)f2b(a) | ((unsigned int)f2b(b) << 16);
}

// ===========================================================================
// Prep mega-kernel (region-branched): cast x -> bf16 | cast weights | hist.
// All three regions are independent; saves 2 launches.
// ===========================================================================
__global__ __launch_bounds__(256) void k_prep(
    const float* __restrict__ x, unsigned short* __restrict__ xb, int n4,
    const float* __restrict__ Wa1, const float* __restrict__ Wb1,
    const float* __restrict__ Wa2, const float* __restrict__ Wb2,
    unsigned short* __restrict__ wa1, unsigned short* __restrict__ wb1,
    unsigned short* __restrict__ wa2, unsigned short* __restrict__ wb2,
    const int* __restrict__ dst, int* __restrict__ counts, int n_edges,
    int cast_blocks, int wblocks)
{
    const int b = blockIdx.x;
    if (b < cast_blocks) {
        int i = b * 256 + threadIdx.x;
        if (i >= n4) return;
        float4 v = reinterpret_cast<const float4*>(x)[i];
        uint2 o;
        o.x = pack2(v.x, v.y);
        o.y = pack2(v.z, v.w);
        reinterpret_cast<uint2*>(xb)[i] = o;
    } else if (b < cast_blocks + wblocks) {
        int i = (b - cast_blocks) * 256 + threadIdx.x;
        if (i < 16384) { wa1[i] = f2b(Wa1[i]); wb1[i] = f2b(Wb1[i]); }
        if (i < 8192)  { wa2[i] = f2b(Wa2[i]); wb2[i] = f2b(Wb2[i]); }
    } else {
        int e = (b - cast_blocks - wblocks) * 256 + threadIdx.x;
        if (e >= n_edges) return;
        atomicAdd(&counts[dst[e]], 1);
    }
}

// ===========================================================================
// CSR build: 2-level scan (13 blocks x 1024 x int4) + place
// ===========================================================================
__global__ __launch_bounds__(1024) void k_scan_local(
    const int* __restrict__ counts, int* __restrict__ rowptr,
    int* __restrict__ bsum, int n)
{
    __shared__ int wsum[16];
    const int lane = threadIdx.x & 63;
    const int wid = threadIdx.x >> 6;
    int i = blockIdx.x * 4096 + threadIdx.x * 4;
    int4 v = make_int4(0, 0, 0, 0);
    if (i + 3 < n) {
        v = *reinterpret_cast<const int4*>(counts + i);
    } else {
        if (i + 0 < n) v.x = counts[i + 0];
        if (i + 1 < n) v.y = counts[i + 1];
        if (i + 2 < n) v.z = counts[i + 2];
    }
    int tot = v.x + v.y + v.z + v.w;
    int s = tot;
#pragma unroll
    for (int off = 1; off < 64; off <<= 1) {
        int t = __shfl_up(s, off);
        if (lane >= off) s += t;
    }
    if (lane == 63) wsum[wid] = s;
    __syncthreads();
    if (wid == 0 && lane < 16) {
        int ws = wsum[lane];
#pragma unroll
        for (int off = 1; off < 16; off <<= 1) {
            int t = __shfl_up(ws, off);
            if (lane >= off) ws += t;
        }
        wsum[lane] = ws;
    }
    __syncthreads();
    int prefix = ((wid > 0) ? wsum[wid - 1] : 0) + (s - tot);
    int4 o;
    o.x = prefix;
    o.y = prefix + v.x;
    o.z = o.y + v.y;
    o.w = o.z + v.z;
    if (i + 3 < n) {
        *reinterpret_cast<int4*>(rowptr + i) = o;
    } else {
        if (i + 0 < n) rowptr[i + 0] = o.x;
        if (i + 1 < n) rowptr[i + 1] = o.y;
        if (i + 2 < n) rowptr[i + 2] = o.z;
    }
    if (threadIdx.x == 1023) bsum[blockIdx.x] = wsum[15];
}

// Adds block offsets; also zeroes cursor for the subsequent k_place (saves a
// memset launch). Block 0 thread 0 writes rowptr[n] = total.
__global__ __launch_bounds__(1024) void k_scan_add(
    int* __restrict__ rowptr, const int* __restrict__ bsum,
    int* __restrict__ cursor, int n, int nblk)
{
    int off = 0, total = 0;
    for (int j = 0; j < nblk; ++j) {
        int b = bsum[j];
        if (j < (int)blockIdx.x) off += b;
        total += b;
    }
    if (blockIdx.x == 0 && threadIdx.x == 0) rowptr[n] = total;
    int i = blockIdx.x * 4096 + threadIdx.x * 4;
    // zero cursor (int4 stores, tail-guarded)
    if (i + 3 < n) {
        *reinterpret_cast<int4*>(cursor + i) = make_int4(0, 0, 0, 0);
    } else {
        if (i + 0 < n) cursor[i + 0] = 0;
        if (i + 1 < n) cursor[i + 1] = 0;
        if (i + 2 < n) cursor[i + 2] = 0;
    }
    if (blockIdx.x == 0) return;                 // offset 0
    if (i + 3 < n) {
        int4 v = *reinterpret_cast<const int4*>(rowptr + i);
        v.x += off; v.y += off; v.z += off; v.w += off;
        *reinterpret_cast<int4*>(rowptr + i) = v;
    } else {
        if (i + 0 < n) rowptr[i + 0] += off;
        if (i + 1 < n) rowptr[i + 1] += off;
        if (i + 2 < n) rowptr[i + 2] += off;
    }
}

__global__ __launch_bounds__(256) void k_place(
    const int* __restrict__ src, const int* __restrict__ dst,
    const int* __restrict__ rowptr, int* __restrict__ cursor,
    int* __restrict__ srcs_sorted, int n_edges)
{
    int e = blockIdx.x * blockDim.x + threadIdx.x;
    if (e >= n_edges) return;
    int d = dst[e];
    int pos = rowptr[d] + atomicAdd(&cursor[d], 1);
    srcs_sorted[pos] = src[e];
}

// ===========================================================================
// Gather-sum (bf16 in / bf16 out, fp32 accumulate): 16 lanes per node, each
// owns 8 contiguous bf16 (16 B); unroll-4 keeps 4 row loads in flight.
// (R6 lesson: do NOT fuse with the GEMM — phase barrier + small grid kills
// latency hiding; this standalone form is the fast one.)
// ===========================================================================
__global__ __launch_bounds__(256) void k_gather_sum(
    const unsigned short* __restrict__ xb, const int* __restrict__ rowptr,
    const int* __restrict__ srcs, unsigned short* __restrict__ aggb)
{
    int node = blockIdx.x * 16 + (threadIdx.x >> 4);
    if (node >= NNODES) return;
    int seg = threadIdx.x & 15;                 // 16B segment within row
    int beg = rowptr[node], end = rowptr[node + 1];
    float acc[8];
#pragma unroll
    for (int i = 0; i < 8; ++i) acc[i] = 0.f;
    int e = beg;
    for (; e + 3 < end; e += 4) {
        int s0 = srcs[e], s1 = srcs[e + 1], s2 = srcs[e + 2], s3 = srcs[e + 3];
        uint4 v0 = *reinterpret_cast<const uint4*>(xb + (size_t)s0 * DIM + seg * 8);
        uint4 v1 = *reinterpret_cast<const uint4*>(xb + (size_t)s1 * DIM + seg * 8);
        uint4 v2 = *reinterpret_cast<const uint4*>(xb + (size_t)s2 * DIM + seg * 8);
        uint4 v3 = *reinterpret_cast<const uint4*>(xb + (size_t)s3 * DIM + seg * 8);
        acc[0] += blo(v0.x) + blo(v1.x) + blo(v2.x) + blo(v3.x);
        acc[1] += bhi(v0.x) + bhi(v1.x) + bhi(v2.x) + bhi(v3.x);
        acc[2] += blo(v0.y) + blo(v1.y) + blo(v2.y) + blo(v3.y);
        acc[3] += bhi(v0.y) + bhi(v1.y) + bhi(v2.y) + bhi(v3.y);
        acc[4] += blo(v0.z) + blo(v1.z) + blo(v2.z) + blo(v3.z);
        acc[5] += bhi(v0.z) + bhi(v1.z) + bhi(v2.z) + bhi(v3.z);
        acc[6] += blo(v0.w) + blo(v1.w) + blo(v2.w) + blo(v3.w);
        acc[7] += bhi(v0.w) + bhi(v1.w) + bhi(v2.w) + bhi(v3.w);
    }
    for (; e < end; ++e) {
        int s0 = srcs[e];
        uint4 v = *reinterpret_cast<const uint4*>(xb + (size_t)s0 * DIM + seg * 8);
        acc[0] += blo(v.x); acc[1] += bhi(v.x);
        acc[2] += blo(v.y); acc[3] += bhi(v.y);
        acc[4] += blo(v.z); acc[5] += bhi(v.z);
        acc[6] += blo(v.w); acc[7] += bhi(v.w);
    }
    uint4 o;
    o.x = pack2(acc[0], acc[1]);
    o.y = pack2(acc[2], acc[3]);
    o.z = pack2(acc[4], acc[5]);
    o.w = pack2(acc[6], acc[7]);
    *reinterpret_cast<uint4*>(aggb + (size_t)node * DIM + seg * 8) = o;
}

// ===========================================================================
// Direct-operand MFMA dual GEMM — no LDS, no barriers.
// Each wave owns 16 rows. A-fragment rows are read once grid-wide straight
// from global (agg / root); B-fragments from the 32/16 KB weight matrices
// (L1/L2-resident, broadcast across waves). 8 K-steps of 32 (4 per operand).
// A/B frag: lane(l16,quad) reads row l16, cols ks*32+quad*8..+7 (one b128).
// C/D frag: col=l16, row=quad*4+reg (m89-verified mapping).
// ks loop unroll-1: full unroll hoists all 72 loads -> VGPR blowup (R1/R4).
// ===========================================================================
template <int BN, bool RELU, bool OUTBF16>
__global__ __launch_bounds__(256) void k_gemm_direct(
    const unsigned short* __restrict__ Ab,   // agg  [n,128] bf16
    const unsigned short* __restrict__ Bb,   // root [n,128] bf16
    const unsigned short* __restrict__ Wa,   // [BN,128] bf16
    const unsigned short* __restrict__ Wb,   // [BN,128] bf16
    const float* __restrict__ bias, void* __restrict__ Cout, int n_nodes)
{
    constexpr int NT = BN / 16;              // 8 (layer1) or 4 (layer2)
    const int tid = threadIdx.x;
    const int wave = tid >> 6;
    const int lane = tid & 63;
    const int quad = lane >> 4;
    const int l16 = lane & 15;
    const int n0 = blockIdx.x * 64;
    const int arow = n0 + wave * 16 + l16;
    const bool ok = arow < n_nodes;

    f32x4 acc[NT];
#pragma unroll
    for (int nt = 0; nt < NT; ++nt) {
        f32x4 z = {0.f, 0.f, 0.f, 0.f};
        acc[nt] = z;
    }

#pragma unroll 1
    for (int ks = 0; ks < 8; ++ks) {
        const unsigned short* __restrict__ Asrc = (ks < 4) ? Ab : Bb;
        const unsigned short* __restrict__ Wsrc = (ks < 4) ? Wa : Wb;
        const int ko = (ks & 3) * 32;
        bf16x8 a = {};
        if (ok)
            a = *reinterpret_cast<const bf16x8*>(
                Asrc + (size_t)arow * DIM + ko + quad * 8);
#pragma unroll
        for (int nt = 0; nt < NT; ++nt) {
            bf16x8 b = *reinterpret_cast<const bf16x8*>(
                Wsrc + (size_t)(nt * 16 + l16) * DIM + ko + quad * 8);
            acc[nt] = __builtin_amdgcn_mfma_f32_16x16x32_bf16(a, b, acc[nt], 0, 0, 0);
        }
    }

    // epilogue: C row = n0 + wave*16 + quad*4 + reg, col = nt*16 + l16
#pragma unroll
    for (int nt = 0; nt < NT; ++nt) {
        int col = nt * 16 + l16;
        float bv = bias[col];
#pragma unroll
        for (int reg = 0; reg < 4; ++reg) {
            int row = n0 + wave * 16 + quad * 4 + reg;
            if (row >= n_nodes) continue;
            float v = acc[nt][reg] + bv;
            if (RELU) v = fmaxf(v, 0.f);
            if (OUTBF16)
                ((unsigned short*)Cout)[(size_t)row * BN + col] = f2b(v);
            else
                ((float*)Cout)[(size_t)row * BN + col] = v;
        }
    }
}

extern "C" void kernel_launch(void* const* d_in, const int* in_sizes, int n_in,
                              void* d_out, int out_size, void* d_ws, size_t ws_size,
                              hipStream_t stream) {
    const float* x       = (const float*)d_in[0];
    const int*   ei      = (const int*)d_in[1];
    const float* W_rel1  = (const float*)d_in[2];
    const float* W_root1 = (const float*)d_in[3];
    const float* b1      = (const float*)d_in[4];
    const float* W_rel2  = (const float*)d_in[5];
    const float* W_root2 = (const float*)d_in[6];
    const float* b2      = (const float*)d_in[7];

    const int n_edges = in_sizes[1] / 2;
    const int* src = ei;
    const int* dst = ei + n_edges;

    // workspace layout (all 16B-aligned)
    const size_t NELEM = (size_t)NNODES * DIM;            // 6.4M
    unsigned short* xb   = (unsigned short*)d_ws;         // 12.8 MB
    unsigned short* aggb = xb + NELEM;                    // 12.8 MB
    unsigned short* tb   = aggb + NELEM;                  // 12.8 MB
    unsigned short* wa1  = tb + NELEM;                    // 16384
    unsigned short* wb1  = wa1 + 16384;
    unsigned short* wa2  = wb1 + 16384;                   // 8192
    unsigned short* wb2  = wa2 + 8192;
    int* rowptr = (int*)(wb2 + 8192);                     // NNODES+4
    int* cursor = rowptr + (NNODES + 4);                  // NNODES
    int* bsum   = cursor + NNODES;                        // 16
    int* srcs   = bsum + 16;                              // n_edges

    float* out = (float*)d_out;

    const int n4 = NNODES * DIM / 4;
    const int cast_blocks = (n4 + 255) / 256;             // 6250
    const int wblocks = 64;
    const int eblocks = (n_edges + 255) / 256;            // 3125
    const int gblocks = (NNODES + 15) / 16;               // 3125
    const int gemm_blocks = (NNODES + 63) / 64;           // 782
    const int sblocks = (NNODES + 4095) / 4096;           // 13

    // ---- prep: cast x, cast weights, histogram (counts in `cursor`) ----
    hipMemsetAsync(cursor, 0, NNODES * sizeof(int), stream);
    k_prep<<<cast_blocks + wblocks + eblocks, 256, 0, stream>>>(
        x, xb, n4, W_rel1, W_root1, W_rel2, W_root2,
        wa1, wb1, wa2, wb2, dst, cursor, n_edges, cast_blocks, wblocks);

    // ---- CSR build ----
    k_scan_local<<<sblocks, 1024, 0, stream>>>(cursor, rowptr, bsum, NNODES);
    k_scan_add<<<sblocks, 1024, 0, stream>>>(rowptr, bsum, cursor, NNODES, sblocks);
    k_place<<<eblocks, 256, 0, stream>>>(src, dst, rowptr, cursor, srcs, n_edges);

    // ---- layer 1: gather(x) -> agg; [agg|x] @ W1 + b1, relu -> tb (bf16) ----
    k_gather_sum<<<gblocks, 256, 0, stream>>>(xb, rowptr, srcs, aggb);
    k_gemm_direct<128, true, true><<<gemm_blocks, 256, 0, stream>>>(
        aggb, xb, wa1, wb1, b1, tb, NNODES);

    // ---- layer 2: gather(tb) -> agg; [agg|tb] @ W2 + b2 -> out (fp32) ----
    k_gather_sum<<<gblocks, 256, 0, stream>>>(tb, rowptr, srcs, aggb);
    k_gemm_direct<64, false, false><<<gemm_blocks, 256, 0, stream>>>(
        aggb, tb, wa2, wb2, b2, out, NNODES);
}